// Round 3
// baseline (30662.524 us; speedup 1.0000x reference)
//
#include <hip/hip_runtime.h>
#include <cstdint>

#define T_STEPS 400
#define B_SZ    256
#define NIN_SZ  64
#define H_SZ    512
#define NOUT_SZ 16
#define NEXC    409            // int(0.8*512)
#define MEMBERS 8              // WGs per group (column slices)
#define GROUPS  32             // batch groups
#define BG      8              // batches per group
#define CSL     64             // columns per member
#define NTHR    512

// ws float-offset layout
#define WS_WRNN  0
#define WS_WIN   (H_SZ * H_SZ)                 // 262144
#define WS_WOUT  (WS_WIN + NIN_SZ * H_SZ)      // 294912
#define WS_FLAGS (WS_WOUT + H_SZ * NOUT_SZ)    // 303104 floats -> byte 1212416

// LDS carve (floats): Wlds 32768 | hpT/pbuf 4096 | xt 512 | h_own 512 | brnn 64
#define LDS_FLOATS (32768 + 4096 + 512 + 512 + 64)   // 37952 -> 151808 B

// ---------------------------------------------------------------------------
__global__ void prep_weights(const float* __restrict__ W_in,
                             const float* __restrict__ W_rnn,
                             const float* __restrict__ W_out,
                             float* __restrict__ ws) {
    int idx = blockIdx.x * blockDim.x + threadIdx.x;
    const int n_rnn = H_SZ * H_SZ;
    const int n_in  = NIN_SZ * H_SZ;
    const int n_out = H_SZ * NOUT_SZ;
    if (idx < n_rnn) {
        int k = idx >> 9;
        float v = fmaxf(W_rnn[idx], 0.0f);
        ws[idx] = (k < NEXC) ? v : -v;
    } else if (idx < n_rnn + n_in) {
        ws[idx] = fmaxf(W_in[idx - n_rnn], 0.0f);
    } else if (idx < n_rnn + n_in + n_out) {
        ws[idx] = fmaxf(W_out[idx - n_rnn - n_in], 0.0f);
    }
}

__global__ void zero_flags(unsigned int* __restrict__ flags) {
    if (threadIdx.x < MEMBERS * GROUPS) flags[threadIdx.x] = 0u;
}

// ---------------------------------------------------------------------------
// Persistent kernel: 256 WGs = 32 batch-groups x 8 column-members.
// W_rnn column-slice lives in LDS for all 400 steps. h exchanged via out_h[t]
// (step-indexed, never overwritten) + per-group monotonic flags.
// bid = m*32+g  => all 8 members of group g share XCD g%8 (perf only).
// ---------------------------------------------------------------------------
__global__ __launch_bounds__(NTHR)
void biornn_main(const float* __restrict__ x,
                 const float* __restrict__ noise,
                 const float* __restrict__ wrnn,
                 const float* __restrict__ win,
                 const float* __restrict__ brnn,
                 unsigned int* __restrict__ flags,
                 float* __restrict__ out_h,
                 float* __restrict__ out_sx,
                 float* __restrict__ out_su) {
    extern __shared__ float smem[];
    float* Wlds   = smem;                      // [512][64]
    float* hpT    = smem + 32768;              // 4096 floats (aliased by pbuf)
    float* xt     = smem + 32768 + 4096;       // [8][64]
    float* h_own  = xt + BG * NIN_SZ;          // [8][64]
    float* brnn_l = h_own + BG * CSL;          // [64]

    const int tid = threadIdx.x;
    const int bid = blockIdx.x;
    const int m   = bid >> 5;          // member 0..7
    const int g   = bid & 31;          // group  0..31
    const int c0  = m * CSL;           // own column base
    const int b0  = g * BG;            // own batch base

    // ---- one-time loads ----
    {
        const int cc = tid & 63, kk = tid >> 6;
        for (int i = 0; i < 64; ++i) {
            int k = i * 8 + kk;
            Wlds[k * 64 + cc] = wrnn[(size_t)k * H_SZ + c0 + cc];
        }
        if (tid < CSL) brnn_l[tid] = brnn[c0 + tid];
        h_own[tid] = 0.1f;             // 512 elems
    }

    // STP state: thread j owns global column j (all 8 batches), redundantly
    // computed by all 8 members of the group (identical fp ops -> identical).
    const int j = tid;
    const bool  fac   = ((j & 1) == 0);
    const float Uj    = fac ? 0.15f : 0.45f;
    const float a_stf = fac ? (10.0f / 1500.0f) : (10.0f / 200.0f);
    const float a_std = fac ? (10.0f / 200.0f)  : (10.0f / 1500.0f);
    float hreg[8], sx[8], su[8];
#pragma unroll
    for (int r = 0; r < 8; ++r) { hreg[r] = 0.1f; sx[r] = 1.0f; su[r] = Uj; }

    const bool own = (j >= c0) && (j < c0 + CSL);

    // C-phase mapping: thread -> (batch cb, local col cc)
    const int cb = tid >> 6;
    const int cc = tid & 63;
    const int kg = tid >> 6;           // B-phase K-group (= wave id)

    __syncthreads();

    for (int t = 0; t < T_STEPS; ++t) {
        // ---------------- phase A ----------------
        xt[(tid >> 6) * NIN_SZ + (tid & 63)] =
            x[((size_t)t * B_SZ + b0 + (tid >> 6)) * NIN_SZ + (tid & 63)];
        // prefetch noise for phase C (hides HBM latency under matvec)
        const float nz = noise[((size_t)t * B_SZ + b0 + cb) * H_SZ + c0 + cc];

        float hp[8];
#pragma unroll
        for (int r = 0; r < 8; ++r) {
            float h_ = hreg[r], sx_ = sx[r], su_ = su[r];
            float sxn = sx_ + a_std * (1.0f - sx_) - 0.01f * su_ * sx_ * h_;
            float sun = su_ + a_stf * (Uj - su_)   + 0.01f * Uj * (1.0f - su_) * h_;
            sxn = fminf(fmaxf(sxn, 0.0f), 1.0f);
            sun = fminf(fmaxf(sun, 0.0f), 1.0f);
            sx[r] = sxn; su[r] = sun;
            hp[r] = sun * sxn * h_;
        }
        {   // swizzled hpT write: float4 slot = 2*j + (half ^ ((j>>2)&1))
            float4* hp4 = (float4*)hpT;
            const int s = (j >> 2) & 1;
            hp4[2 * j + s]       = make_float4(hp[0], hp[1], hp[2], hp[3]);
            hp4[2 * j + (1 - s)] = make_float4(hp[4], hp[5], hp[6], hp[7]);
        }
        if (own) {
            const size_t ob = ((size_t)t * B_SZ + b0) * H_SZ + j;
#pragma unroll
            for (int r = 0; r < 8; ++r) {
                out_sx[ob + (size_t)r * H_SZ] = sx[r];
                out_su[ob + (size_t)r * H_SZ] = su[r];
            }
        }
        __syncthreads();                              // bar0

        // ---------------- phase B: matvec (W from LDS) ----------------
        float acc[8];
#pragma unroll
        for (int r = 0; r < 8; ++r) acc[r] = 0.0f;
        {
            const float4* hp4 = (const float4*)hpT;
#pragma unroll 8
            for (int k = kg * 64; k < kg * 64 + 64; ++k) {
                const float w = Wlds[k * 64 + cc];
                const int s = (k >> 2) & 1;
                const float4 a  = hp4[2 * k + s];
                const float4 bb = hp4[2 * k + (1 - s)];
                acc[0] = fmaf(w, a.x,  acc[0]);
                acc[1] = fmaf(w, a.y,  acc[1]);
                acc[2] = fmaf(w, a.z,  acc[2]);
                acc[3] = fmaf(w, a.w,  acc[3]);
                acc[4] = fmaf(w, bb.x, acc[4]);
                acc[5] = fmaf(w, bb.y, acc[5]);
                acc[6] = fmaf(w, bb.z, acc[6]);
                acc[7] = fmaf(w, bb.w, acc[7]);
            }
        }
        __syncthreads();                              // bar1: hpT reads done
        {   // K-partials into pbuf (aliases hpT region)
            float* pbuf = hpT;
#pragma unroll
            for (int r = 0; r < 8; ++r)
                pbuf[kg * 512 + r * 64 + cc] = acc[r];
        }
        __syncthreads();                              // bar2

        // ---------------- phase C: combine + input proj + membrane ----------------
        {
            const float* pbuf = hpT;
            float ssum = brnn_l[cc];
#pragma unroll
            for (int q = 0; q < 8; ++q)
                ssum += pbuf[q * 512 + cb * 64 + cc];
#pragma unroll 8
            for (int k = 0; k < NIN_SZ; ++k)
                ssum = fmaf(xt[cb * NIN_SZ + k], win[(size_t)k * H_SZ + c0 + cc], ssum);
            const float hn =
                fmaxf(0.9f * h_own[cb * 64 + cc] + 0.1f * ssum + nz, 0.0f);
            out_h[((size_t)t * B_SZ + b0 + cb) * H_SZ + c0 + cc] = hn;
        }

        // ---------------- publish / group barrier / gather ----------------
        if (t < T_STEPS - 1) {
            __threadfence();                          // release own out_h slice
            __syncthreads();
            if (tid == 0)
                __hip_atomic_store(&flags[bid], (unsigned)(t + 1),
                                   __ATOMIC_RELEASE, __HIP_MEMORY_SCOPE_AGENT);
            if (tid < MEMBERS) {
                while (__hip_atomic_load(&flags[tid * 32 + g],
                                         __ATOMIC_ACQUIRE,
                                         __HIP_MEMORY_SCOPE_AGENT)
                       < (unsigned)(t + 1)) {
                    __builtin_amdgcn_s_sleep(2);
                }
            }
            __syncthreads();
            __threadfence();                          // acquire peers' slices
            // gather full h(t) for column j across own 8 batches
            const size_t gb = ((size_t)t * B_SZ + b0) * H_SZ + j;
#pragma unroll
            for (int r = 0; r < 8; ++r)
                hreg[r] = out_h[gb + (size_t)r * H_SZ];
            if (own) {
#pragma unroll
                for (int r = 0; r < 8; ++r)
                    h_own[r * 64 + (j - c0)] = hreg[r];
            }
            // next A's hpT writes vs this C's pbuf reads: separated by the
            // publish __syncthreads; h_own writes vs next C reads: bar0-bar2.
        }
    }
}

// ---------------------------------------------------------------------------
// logits[t,b,:] = h[t,b,:] @ Wout_eff + bout   (after the scan completes)
// ---------------------------------------------------------------------------
__global__ __launch_bounds__(256)
void logits_k(const float* __restrict__ h, const float* __restrict__ wout,
              const float* __restrict__ bout, float* __restrict__ out) {
    __shared__ float wl[H_SZ * NOUT_SZ];   // 32 KB
    __shared__ float bl[NOUT_SZ];
    const int tid = threadIdx.x;
    for (int i = tid; i < H_SZ * NOUT_SZ; i += 256) wl[i] = wout[i];
    if (tid < NOUT_SZ) bl[tid] = bout[tid];
    __syncthreads();
    const size_t row = (size_t)blockIdx.x * 16 + (tid >> 4);
    const int o = tid & 15;
    const float* hr = h + row * H_SZ;
    float s = bl[o];
#pragma unroll 8
    for (int jj = 0; jj < H_SZ; ++jj)
        s = fmaf(hr[jj], wl[jj * NOUT_SZ + o], s);
    out[row * NOUT_SZ + o] = s;
}

extern "C" void kernel_launch(void* const* d_in, const int* in_sizes, int n_in,
                              void* d_out, int out_size, void* d_ws, size_t ws_size,
                              hipStream_t stream) {
    const float* x     = (const float*)d_in[0];
    const float* noise = (const float*)d_in[1];
    const float* W_in  = (const float*)d_in[2];
    const float* W_rnn = (const float*)d_in[3];
    const float* b_rnn = (const float*)d_in[4];
    const float* W_out = (const float*)d_in[5];
    const float* b_out = (const float*)d_in[6];

    float* ws       = (float*)d_ws;
    float* wrnn_eff = ws + WS_WRNN;
    float* win_eff  = ws + WS_WIN;
    float* wout_eff = ws + WS_WOUT;
    unsigned int* flags = (unsigned int*)(ws + WS_FLAGS);

    float* out_logits = (float*)d_out;
    float* out_h  = out_logits + (size_t)T_STEPS * B_SZ * NOUT_SZ;
    float* out_sx = out_h  + (size_t)T_STEPS * B_SZ * H_SZ;
    float* out_su = out_sx + (size_t)T_STEPS * B_SZ * H_SZ;

    const int total = H_SZ * H_SZ + NIN_SZ * H_SZ + H_SZ * NOUT_SZ;
    prep_weights<<<(total + 255) / 256, 256, 0, stream>>>(W_in, W_rnn, W_out, ws);
    zero_flags<<<1, 256, 0, stream>>>(flags);

    biornn_main<<<MEMBERS * GROUPS, NTHR, LDS_FLOATS * sizeof(float), stream>>>(
        x, noise, wrnn_eff, win_eff, b_rnn, flags, out_h, out_sx, out_su);

    logits_k<<<(T_STEPS * B_SZ) / 16, 256, 0, stream>>>(
        out_h, wout_eff, b_out, out_logits);
}

// Round 4
// 2911.456 us; speedup vs baseline: 10.5317x; 10.5317x over previous
//
#include <hip/hip_runtime.h>
#include <cstdint>

#define T_STEPS 400
#define B_SZ    256
#define NIN_SZ  64
#define H_SZ    512
#define NOUT_SZ 16
#define NEXC    409            // int(0.8*512)
#define MEMBERS 8              // column-slice members per group
#define GROUPS  32             // batch groups
#define BG      8              // batches per group
#define CSL     64             // columns per member
#define NTHR    512
#define KEXT    576            // 512 recurrent + 64 input rows folded in
#define KG      32             // K-split groups (one per 16-thread slice)
#define KR      18             // k rows per thread (576/32)

// ws float-offset layout
#define WS_WRNN  0
#define WS_WIN   (H_SZ * H_SZ)                 // 262144
#define WS_WOUT  (WS_WIN + NIN_SZ * H_SZ)      // 294912
#define WS_FLAGS (WS_WOUT + H_SZ * NOUT_SZ)    // 303104

// dynamic LDS floats: hpT[576][8] | pbuf[32][8][64] | h_own[8][64] | brnn[64]
#define LDS_FLOATS (KEXT * 8 + KG * 8 * 64 + 512 + 64)   // 21568 -> 86272 B

// ---------------------------------------------------------------------------
__global__ void prep_weights(const float* __restrict__ W_in,
                             const float* __restrict__ W_rnn,
                             const float* __restrict__ W_out,
                             float* __restrict__ ws) {
    int idx = blockIdx.x * blockDim.x + threadIdx.x;
    const int n_rnn = H_SZ * H_SZ;
    const int n_in  = NIN_SZ * H_SZ;
    const int n_out = H_SZ * NOUT_SZ;
    if (idx < n_rnn) {
        int k = idx >> 9;
        float v = fmaxf(W_rnn[idx], 0.0f);
        ws[idx] = (k < NEXC) ? v : -v;
    } else if (idx < n_rnn + n_in) {
        ws[idx] = fmaxf(W_in[idx - n_rnn], 0.0f);
    } else if (idx < n_rnn + n_in + n_out) {
        ws[idx] = fmaxf(W_out[idx - n_rnn - n_in], 0.0f);
    }
}

__global__ void zero_flags(unsigned int* __restrict__ flags) {
    if (threadIdx.x < MEMBERS * GROUPS) flags[threadIdx.x] = 0u;
}

#define FMA4(a, w, s)            \
    a.x = fmaf(w.x, s, a.x);     \
    a.y = fmaf(w.y, s, a.y);     \
    a.z = fmaf(w.z, s, a.z);     \
    a.w = fmaf(w.w, s, a.w);

// ---------------------------------------------------------------------------
// 256 WGs = 32 batch-groups x 8 column-members. W-slice in REGISTERS
// (72 VGPR/thread, loaded once). h exchanged via sc0/sc1 global ops (coherent
// at chip level, XCD-placement independent, no cache-invalidate instructions).
// ---------------------------------------------------------------------------
__global__ __launch_bounds__(NTHR, 2)
void biornn_main(const float* __restrict__ x,
                 const float* __restrict__ noise,
                 const float* __restrict__ wrnn,
                 const float* __restrict__ win,
                 const float* __restrict__ brnn,
                 unsigned int* __restrict__ flags,
                 float* __restrict__ out_h,
                 float* __restrict__ out_sx,
                 float* __restrict__ out_su) {
    extern __shared__ float smem[];
    float* hpT    = smem;                       // [KEXT][8]
    float* pbuf   = smem + KEXT * 8;            // [KG][8][64]
    float* h_own  = pbuf + KG * 8 * 64;         // [8][64]
    float* brnn_l = h_own + 512;                // [64]

    const int tid = threadIdx.x;
    const int bid = blockIdx.x;
    const int m   = bid >> 5;          // member 0..7
    const int g   = bid & 31;          // group  0..31
    const int c0  = m * CSL;
    const int b0  = g * BG;

    // phase-B mapping
    const int kg  = tid >> 4;          // 0..31
    const int ccg = tid & 15;          // 0..15 (4 cols each)
    // phase-C mapping
    const int cb  = tid >> 6;          // batch 0..7
    const int cc  = tid & 63;          // own col 0..63

    // ---- one-time: W slice into registers (recurrent rows + input rows) ----
    float4 Wv[KR];
#pragma unroll
    for (int i = 0; i < KR; ++i) {
        const int k = kg * KR + i;
        const float* src = (k < H_SZ)
            ? &wrnn[(size_t)k * H_SZ + c0 + ccg * 4]
            : &win[(size_t)(k - H_SZ) * H_SZ + c0 + ccg * 4];
        Wv[i] = *(const float4*)src;
    }
    if (tid < CSL) brnn_l[tid] = brnn[c0 + tid];
    h_own[tid] = 0.1f;

    // STP state: thread j owns column j for the group's 8 batches
    const int j = tid;
    const bool  fac   = ((j & 1) == 0);
    const float Uj    = fac ? 0.15f : 0.45f;
    const float a_stf = fac ? (10.0f / 1500.0f) : (10.0f / 200.0f);
    const float a_std = fac ? (10.0f / 200.0f)  : (10.0f / 1500.0f);
    float hreg[8], sx[8], su[8];
#pragma unroll
    for (int r = 0; r < 8; ++r) { hreg[r] = 0.1f; sx[r] = 1.0f; su[r] = Uj; }
    const bool own = (j >= c0) && (j < c0 + CSL);
    __syncthreads();

    for (int t = 0; t < T_STEPS; ++t) {
        // ---------------- phase A: STP + stage hpT + x rows ----------------
        const float nz = noise[((size_t)t * B_SZ + b0 + cb) * H_SZ + c0 + cc];
        {
            float hp[8];
#pragma unroll
            for (int r = 0; r < 8; ++r) {
                float h_ = hreg[r], sx_ = sx[r], su_ = su[r];
                float sxn = sx_ + a_std * (1.0f - sx_) - 0.01f * su_ * sx_ * h_;
                float sun = su_ + a_stf * (Uj - su_)   + 0.01f * Uj * (1.0f - su_) * h_;
                sxn = fminf(fmaxf(sxn, 0.0f), 1.0f);
                sun = fminf(fmaxf(sun, 0.0f), 1.0f);
                sx[r] = sxn; su[r] = sun; hp[r] = sun * sxn * h_;
            }
            ((float4*)hpT)[j * 2]     = make_float4(hp[0], hp[1], hp[2], hp[3]);
            ((float4*)hpT)[j * 2 + 1] = make_float4(hp[4], hp[5], hp[6], hp[7]);
        }
        if (own) {
            const size_t ob = ((size_t)t * B_SZ + b0) * H_SZ + j;
#pragma unroll
            for (int r = 0; r < 8; ++r) {
                out_sx[ob + (size_t)r * H_SZ] = sx[r];
                out_su[ob + (size_t)r * H_SZ] = su[r];
            }
        }
        if (tid < NIN_SZ) {
#pragma unroll
            for (int r = 0; r < 8; ++r)
                hpT[(H_SZ + tid) * 8 + r] =
                    x[((size_t)t * B_SZ + b0 + r) * NIN_SZ + tid];
        }
        __syncthreads();

        // ---------------- phase B: matvec, W in registers ----------------
        float4 acc[8];
#pragma unroll
        for (int r = 0; r < 8; ++r) acc[r] = make_float4(0.f, 0.f, 0.f, 0.f);
        {
            const float4* hp4 = (const float4*)hpT;
            const int kbase = kg * KR;
#pragma unroll
            for (int i = 0; i < KR; ++i) {
                const float4 L  = hp4[(kbase + i) * 2];
                const float4 Hh = hp4[(kbase + i) * 2 + 1];
                const float4 w  = Wv[i];
                FMA4(acc[0], w, L.x)  FMA4(acc[1], w, L.y)
                FMA4(acc[2], w, L.z)  FMA4(acc[3], w, L.w)
                FMA4(acc[4], w, Hh.x) FMA4(acc[5], w, Hh.y)
                FMA4(acc[6], w, Hh.z) FMA4(acc[7], w, Hh.w)
            }
        }
#pragma unroll
        for (int r = 0; r < 8; ++r)
            *(float4*)&pbuf[(kg * 8 + r) * 64 + ccg * 4] = acc[r];
        __syncthreads();

        // ---------------- phase C: reduce + membrane + publish h ----------------
        {
            float s = brnn_l[cc];
#pragma unroll
            for (int q = 0; q < KG; ++q)
                s += pbuf[(q * 8 + cb) * 64 + cc];
            const float hn =
                fmaxf(0.9f * h_own[cb * 64 + cc] + 0.1f * s + nz, 0.0f);
            h_own[cb * 64 + cc] = hn;
            float* hp_ = out_h + ((size_t)t * B_SZ + b0 + cb) * H_SZ + c0 + cc;
            asm volatile("global_store_dword %0, %1, off sc0 sc1"
                         :: "v"(hp_), "v"(hn) : "memory");
        }

        if (t == T_STEPS - 1) break;

        // ---------------- flag publish / poll / gather ----------------
        asm volatile("s_waitcnt vmcnt(0)" ::: "memory");
        __syncthreads();                       // all members' h stores drained
        if (tid == 0) {
            unsigned int* fp = &flags[bid];
            unsigned int  tv = (unsigned)(t + 1);
            asm volatile("global_store_dword %0, %1, off sc0 sc1"
                         :: "v"(fp), "v"(tv) : "memory");
        }
        if (tid < MEMBERS) {
            const unsigned int want = (unsigned)(t + 1);
            unsigned int* fp = &flags[tid * GROUPS + g];
            unsigned int v;
            while (true) {
                asm volatile("global_load_dword %0, %1, off sc0 sc1\n\t"
                             "s_waitcnt vmcnt(0)"
                             : "=v"(v) : "v"(fp) : "memory");
                if (v >= want) break;
                __builtin_amdgcn_s_sleep(2);
            }
        }
        __syncthreads();
        {   // gather full h(t) for column j, 8 batches (bypass L1/L2: sc0 sc1)
            const float* q0 = out_h + ((size_t)t * B_SZ + b0) * H_SZ + j;
            const float* q2 = q0 + 2 * H_SZ;
            const float* q4 = q0 + 4 * H_SZ;
            const float* q6 = q0 + 6 * H_SZ;
            float g0, g1, g2, g3, g4, g5, g6, g7;
            asm volatile(
                "global_load_dword %0, %8,  off sc0 sc1\n\t"
                "global_load_dword %1, %8,  off offset:2048 sc0 sc1\n\t"
                "global_load_dword %2, %9,  off sc0 sc1\n\t"
                "global_load_dword %3, %9,  off offset:2048 sc0 sc1\n\t"
                "global_load_dword %4, %10, off sc0 sc1\n\t"
                "global_load_dword %5, %10, off offset:2048 sc0 sc1\n\t"
                "global_load_dword %6, %11, off sc0 sc1\n\t"
                "global_load_dword %7, %11, off offset:2048 sc0 sc1\n\t"
                "s_waitcnt vmcnt(0)"
                : "=&v"(g0), "=&v"(g1), "=&v"(g2), "=&v"(g3),
                  "=&v"(g4), "=&v"(g5), "=&v"(g6), "=&v"(g7)
                : "v"(q0), "v"(q2), "v"(q4), "v"(q6)
                : "memory");
            hreg[0] = g0; hreg[1] = g1; hreg[2] = g2; hreg[3] = g3;
            hreg[4] = g4; hreg[5] = g5; hreg[6] = g6; hreg[7] = g7;
        }
    }
}

// ---------------------------------------------------------------------------
// logits[t,b,:] = h[t,b,:] @ Wout_eff + bout
// ---------------------------------------------------------------------------
__global__ __launch_bounds__(256)
void logits_k(const float* __restrict__ h, const float* __restrict__ wout,
              const float* __restrict__ bout, float* __restrict__ out) {
    __shared__ float wl[H_SZ * 17];    // padded: row stride 17
    __shared__ float bl[NOUT_SZ];
    const int tid = threadIdx.x;
    for (int i = tid; i < H_SZ * NOUT_SZ; i += 256)
        wl[(i >> 4) * 17 + (i & 15)] = wout[i];
    if (tid < NOUT_SZ) bl[tid] = bout[tid];
    __syncthreads();
    const size_t row = (size_t)blockIdx.x * 16 + (tid >> 4);
    const int o = tid & 15;
    const float* hr = h + row * H_SZ;
    float s = bl[o];
#pragma unroll 8
    for (int jj = 0; jj < H_SZ; ++jj)
        s = fmaf(hr[jj], wl[jj * 17 + o], s);
    out[row * NOUT_SZ + o] = s;
}

extern "C" void kernel_launch(void* const* d_in, const int* in_sizes, int n_in,
                              void* d_out, int out_size, void* d_ws, size_t ws_size,
                              hipStream_t stream) {
    const float* x     = (const float*)d_in[0];
    const float* noise = (const float*)d_in[1];
    const float* W_in  = (const float*)d_in[2];
    const float* W_rnn = (const float*)d_in[3];
    const float* b_rnn = (const float*)d_in[4];
    const float* W_out = (const float*)d_in[5];
    const float* b_out = (const float*)d_in[6];

    float* ws       = (float*)d_ws;
    float* wrnn_eff = ws + WS_WRNN;
    float* win_eff  = ws + WS_WIN;
    float* wout_eff = ws + WS_WOUT;
    unsigned int* flags = (unsigned int*)(ws + WS_FLAGS);

    float* out_logits = (float*)d_out;
    float* out_h  = out_logits + (size_t)T_STEPS * B_SZ * NOUT_SZ;
    float* out_sx = out_h  + (size_t)T_STEPS * B_SZ * H_SZ;
    float* out_su = out_sx + (size_t)T_STEPS * B_SZ * H_SZ;

    const int total = H_SZ * H_SZ + NIN_SZ * H_SZ + H_SZ * NOUT_SZ;
    prep_weights<<<(total + 255) / 256, 256, 0, stream>>>(W_in, W_rnn, W_out, ws);
    zero_flags<<<1, 256, 0, stream>>>(flags);

    biornn_main<<<MEMBERS * GROUPS, NTHR, LDS_FLOATS * sizeof(float), stream>>>(
        x, noise, wrnn_eff, win_eff, b_rnn, flags, out_h, out_sx, out_su);

    logits_k<<<(T_STEPS * B_SZ) / 16, 256, 0, stream>>>(
        out_h, wout_eff, b_out, out_logits);
}